// Round 3
// baseline (747.210 us; speedup 1.0000x reference)
//
#include <hip/hip_runtime.h>
#include <cstdint>
#include <cstddef>

typedef unsigned short u16;
typedef short short8 __attribute__((ext_vector_type(8)));
typedef float f32x4 __attribute__((ext_vector_type(4)));

__device__ __forceinline__ u16 f2bf(float f) {
  union { float f; unsigned u; } x; x.f = f;
  unsigned r = x.u + 0x7FFFu + ((x.u >> 16) & 1u);   // RNE
  return (u16)(r >> 16);
}
__device__ __forceinline__ float b2f(u16 h) {
  union { unsigned u; float f; } x; x.u = ((unsigned)h) << 16;
  return x.f;
}
__device__ __forceinline__ float silu_f(float v) {
  return v / (1.f + __expf(-v));
}
__device__ __forceinline__ void gll(const u16* g, u16* l) {
  __builtin_amdgcn_global_load_lds((const __attribute__((address_space(1))) unsigned*)g,
                                   (__attribute__((address_space(3))) unsigned*)l, 16, 0, 0);
}

// ---------------- f32 -> bf16 conversion (vectorized) ----------------
__global__ __launch_bounds__(256) void cvt_k(const float4* __restrict__ in,
                                             ushort4* __restrict__ out, int n4) {
  int i = blockIdx.x * 256 + threadIdx.x;
  if (i >= n4) return;
  float4 v = in[i];
  ushort4 o;
  o.x = f2bf(v.x); o.y = f2bf(v.y); o.z = f2bf(v.z); o.w = f2bf(v.w);
  out[i] = o;
}

// ---------------- LayerNorm over 256 cols; bf16 out (+ optional transposed copy) ----------------
__global__ __launch_bounds__(256) void ln_k(const float* __restrict__ in,
                                            const float* __restrict__ g,
                                            const float* __restrict__ b,
                                            u16* __restrict__ out,
                                            u16* __restrict__ outT) {
  const int row = blockIdx.x;
  const int a = threadIdx.x;
  float v = in[(size_t)row * 256 + a];
  float s = v, s2 = v * v;
#pragma unroll
  for (int o = 32; o; o >>= 1) { s += __shfl_down(s, o, 64); s2 += __shfl_down(s2, o, 64); }
  __shared__ float red[8];
  int l = a & 63, w = a >> 6;
  if (l == 0) { red[w] = s; red[4 + w] = s2; }
  __syncthreads();
  s  = red[0] + red[1] + red[2] + red[3];
  s2 = red[4] + red[5] + red[6] + red[7];
  float mu  = s * 0.00390625f;
  float var = s2 * 0.00390625f - mu * mu;
  float rs  = rsqrtf(var + 1e-5f);
  float o   = (v - mu) * rs * g[a] + b[a];
  u16 ob = f2bf(o);
  out[(size_t)row * 256 + a] = ob;
  if (outT) {
    int bi = row >> 11, t = row & 2047;
    outT[((size_t)bi * 256 + a) * 2048 + t] = ob;
  }
}

// ================= 128x128 2-phase GEMM — kept for N=256 shapes ============
// EPI: 0 = f32 store, 1 = bf16 store
template <int EPI>
__global__ __launch_bounds__(256) void gemm_bt(const u16* __restrict__ A,
                                               const u16* __restrict__ B,
                                               void* __restrict__ Cv,
                                               int M, int N, int K,
                                               long bA, long bB, long bC) {
  __shared__ u16 Al[128 * 64];
  __shared__ u16 Bl[128 * 64];
  const int tid  = threadIdx.x;
  const int bz   = blockIdx.z;
  const int brow = blockIdx.y * 128;
  const int bcol = blockIdx.x * 128;
  A += (size_t)bz * bA;
  B += (size_t)bz * bB;
  const int lane = tid & 63;
  const int w = tid >> 6, wr = w >> 1, wc = w & 1;
  const int srow = tid >> 3;
  const int scol = (tid & 7) * 8;

  f32x4 acc[4][4] = {};

  for (int kt = 0; kt < K; kt += 64) {
#pragma unroll
    for (int i = 0; i < 4; ++i)
      gll(A + (size_t)(brow + i * 32 + srow) * K + kt + scol, &Al[(i * 256 + tid) * 8]);
#pragma unroll
    for (int i = 0; i < 4; ++i)
      gll(B + (size_t)(bcol + i * 32 + srow) * K + kt + scol, &Bl[(i * 256 + tid) * 8]);
    __syncthreads();
#pragma unroll
    for (int kk = 0; kk < 2; ++kk) {
      short8 af[4], bfr[4];
      const int ko = kk * 32 + (lane >> 4) * 8;
#pragma unroll
      for (int m = 0; m < 4; ++m)
        af[m] = *(const short8*)&Al[(wr * 64 + m * 16 + (lane & 15)) * 64 + ko];
#pragma unroll
      for (int n = 0; n < 4; ++n)
        bfr[n] = *(const short8*)&Bl[(wc * 64 + n * 16 + (lane & 15)) * 64 + ko];
#pragma unroll
      for (int m = 0; m < 4; ++m)
#pragma unroll
        for (int n = 0; n < 4; ++n)
          acc[m][n] = __builtin_amdgcn_mfma_f32_16x16x32_bf16(af[m], bfr[n], acc[m][n], 0, 0, 0);
    }
    __syncthreads();
  }

  const int col0 = bcol + wc * 64 + (lane & 15);
  const int row0 = brow + wr * 64 + ((lane >> 4) << 2);
  if (EPI == 0) {
    float* Cf = (float*)Cv + (size_t)bz * bC;
#pragma unroll
    for (int m = 0; m < 4; ++m)
#pragma unroll
      for (int j = 0; j < 4; ++j) {
        size_t roff = (size_t)(row0 + m * 16 + j) * N + col0;
#pragma unroll
        for (int n = 0; n < 4; ++n) Cf[roff + n * 16] = acc[m][n][j];
      }
  } else {
    u16* Cb = (u16*)Cv + (size_t)bz * bC;
#pragma unroll
    for (int m = 0; m < 4; ++m)
#pragma unroll
      for (int j = 0; j < 4; ++j) {
        size_t roff = (size_t)(row0 + m * 16 + j) * N + col0;
#pragma unroll
        for (int n = 0; n < 4; ++n) Cb[roff + n * 16] = f2bf(acc[m][n][j]);
      }
  }
}

// ================= 256x256 8-wave pipelined GEMM (T1+T2+T3+T4-counted+T5) =================
// C[M,N] = A[M,K] @ B[N,K]^T.  BK=64, 512 threads (2x4 waves), LDS 128 KiB double-buffered.
// Counted-vmcnt staging rotation: A(t+1) issued at boundary of t-1, B(t+1) at t.p1,
// A(t+2) at t.p3; fence = vmcnt(4) (never 0 in steady state).
// EPI: 0=f32, 1=bf16, 2=silu(clip(v,-5,5)) bf16, 3=bf16(H+0.1*v), 4=bf16(silu(v)*H)
template <int EPI>
__global__ __launch_bounds__(512, 2) void gemm256(const u16* __restrict__ A,
                                                  const u16* __restrict__ B,
                                                  void* __restrict__ Cv,
                                                  const u16* __restrict__ H,
                                                  int M, int N, int K,
                                                  long bA, long bB, long bC) {
  __shared__ __align__(16) u16 As[32768];  // [2 buf][2 half][128][64]
  __shared__ __align__(16) u16 Bs[32768];

  const int tid = threadIdx.x;
  const int bz  = blockIdx.z;
  A += (size_t)bz * bA;
  B += (size_t)bz * bB;

  // T1: bijective XCD swizzle (m204)
  const int gx = gridDim.x;
  const int nwg = gx * gridDim.y;
  int orig = blockIdx.y * gx + blockIdx.x;
  {
    int q = nwg >> 3, r = nwg & 7;
    int xcd = orig & 7, idx = orig >> 3;
    orig = (xcd < r) ? xcd * (q + 1) + idx : r * (q + 1) + (xcd - r) * q + idx;
  }
  const int brow = (orig / gx) * 256;
  const int bcol = (orig % gx) * 256;

  const int lane = tid & 63;
  const int wid  = tid >> 6;
  const int wm = wid >> 2, wn = wid & 3;   // 2 x 4 waves

  const int srow = tid >> 3;
  const int scol = ((((tid & 7) << 4) ^ ((srow & 7) << 4)) >> 1);  // u16 units, T2 swizzle
  const u16* Abase = A + (size_t)(brow + srow) * K + scol;
  const u16* Bbase = B + (size_t)(bcol + srow) * K + scol;

  const int fr  = lane & 15;
  const int cs0 = ((((lane >> 4) << 4) ^ ((lane & 7) << 4)) >> 1);
  const int cs1 = cs0 ^ 32;
  const int bro = (wn & 1) * 64;

  const int NT = K >> 6;

  f32x4 acc[8][4] = {};

  auto stageA = [&](int tt) {
    const int buf = tt & 1;
    const int kb = tt << 6;
#pragma unroll
    for (int h = 0; h < 2; ++h) {
      const u16* s = Abase + (size_t)(h * 128) * K + kb;
      u16* d = &As[(buf * 2 + h) * 8192 + tid * 8];
      gll(s, d); gll(s + (size_t)64 * K, d + 4096);
    }
  };
  auto stageB = [&](int tt) {
    const int buf = tt & 1;
    const int kb = tt << 6;
#pragma unroll
    for (int h = 0; h < 2; ++h) {
      const u16* s = Bbase + (size_t)(h * 128) * K + kb;
      u16* d = &Bs[(buf * 2 + h) * 8192 + tid * 8];
      gll(s, d); gll(s + (size_t)64 * K, d + 4096);
    }
  };

  // ---- prologue: A(0), B(0), A(1); counted fence ----
  stageA(0);
  stageB(0);
  if (NT > 1) stageA(1);
  asm volatile("s_waitcnt vmcnt(4)" ::: "memory");  // tile 0 landed; A(1) in flight
  __builtin_amdgcn_s_barrier();

  for (int t = 0; t < NT; ++t) {
    const int cur = t & 1;
    const u16* aH = &As[(cur * 2 + wm) * 8192];
    const u16* bH = &Bs[(cur * 2 + (wn >> 1)) * 8192];
    short8 af[4], bf[4];

    // ---------- phase 0: mq=0, kq=0 ----------
#pragma unroll
    for (int m = 0; m < 4; ++m) af[m] = *(const short8*)(aH + (m * 16 + fr) * 64 + cs0);
#pragma unroll
    for (int n = 0; n < 4; ++n) bf[n] = *(const short8*)(bH + (bro + n * 16 + fr) * 64 + cs0);
    __builtin_amdgcn_s_barrier();
    asm volatile("s_waitcnt lgkmcnt(0)" ::: "memory");
    __builtin_amdgcn_s_setprio(1);
#pragma unroll
    for (int m = 0; m < 4; ++m)
#pragma unroll
      for (int n = 0; n < 4; ++n)
        acc[m][n] = __builtin_amdgcn_mfma_f32_16x16x32_bf16(af[m], bf[n], acc[m][n], 0, 0, 0);
    __builtin_amdgcn_s_setprio(0);
    __builtin_amdgcn_s_barrier();

    // ---------- phase 1: mq=1, kq=0; issue B(t+1) ----------
#pragma unroll
    for (int m = 0; m < 4; ++m) af[m] = *(const short8*)(aH + (64 + m * 16 + fr) * 64 + cs0);
    if (t + 1 < NT) stageB(t + 1);
    __builtin_amdgcn_s_barrier();
    asm volatile("s_waitcnt lgkmcnt(0)" ::: "memory");
    __builtin_amdgcn_s_setprio(1);
#pragma unroll
    for (int m = 0; m < 4; ++m)
#pragma unroll
      for (int n = 0; n < 4; ++n)
        acc[4 + m][n] = __builtin_amdgcn_mfma_f32_16x16x32_bf16(af[m], bf[n], acc[4 + m][n], 0, 0, 0);
    __builtin_amdgcn_s_setprio(0);
    __builtin_amdgcn_s_barrier();

    // ---------- phase 2: mq=0, kq=1 ----------
#pragma unroll
    for (int m = 0; m < 4; ++m) af[m] = *(const short8*)(aH + (m * 16 + fr) * 64 + cs1);
#pragma unroll
    for (int n = 0; n < 4; ++n) bf[n] = *(const short8*)(bH + (bro + n * 16 + fr) * 64 + cs1);
    __builtin_amdgcn_s_barrier();
    asm volatile("s_waitcnt lgkmcnt(0)" ::: "memory");
    __builtin_amdgcn_s_setprio(1);
#pragma unroll
    for (int m = 0; m < 4; ++m)
#pragma unroll
      for (int n = 0; n < 4; ++n)
        acc[m][n] = __builtin_amdgcn_mfma_f32_16x16x32_bf16(af[m], bf[n], acc[m][n], 0, 0, 0);
    __builtin_amdgcn_s_setprio(0);
    __builtin_amdgcn_s_barrier();

    // ---------- phase 3: mq=1, kq=1; issue A(t+2); counted tile fence ----------
#pragma unroll
    for (int m = 0; m < 4; ++m) af[m] = *(const short8*)(aH + (64 + m * 16 + fr) * 64 + cs1);
    __builtin_amdgcn_s_barrier();
    asm volatile("s_waitcnt lgkmcnt(0)" ::: "memory");
    __builtin_amdgcn_s_setprio(1);
#pragma unroll
    for (int m = 0; m < 4; ++m)
#pragma unroll
      for (int n = 0; n < 4; ++n)
        acc[4 + m][n] = __builtin_amdgcn_mfma_f32_16x16x32_bf16(af[m], bf[n], acc[4 + m][n], 0, 0, 0);
    __builtin_amdgcn_s_setprio(0);
    if (t + 2 < NT) stageA(t + 2);          // buf parity of t+2 == cur; readers one barrier behind
    if (t + 1 < NT) {
      if (t + 2 < NT) asm volatile("s_waitcnt vmcnt(4)" ::: "memory");  // t+1 landed; A(t+2) in flight
      else            asm volatile("s_waitcnt vmcnt(0)" ::: "memory");  // penultimate tile
    }
    __builtin_amdgcn_s_barrier();
  }

  // ---- epilogue.  C/D layout: col = lane&15, row = (lane>>4)*4 + reg ----
  const int col0 = bcol + wn * 64 + fr;
  const int row0 = brow + wm * 128 + ((lane >> 4) << 2);

  if (EPI == 0) {
    float* Cf = (float*)Cv + (size_t)bz * bC;
#pragma unroll
    for (int m = 0; m < 8; ++m)
#pragma unroll
      for (int j = 0; j < 4; ++j) {
        size_t roff = (size_t)(row0 + m * 16 + j) * N + col0;
#pragma unroll
        for (int n = 0; n < 4; ++n) Cf[roff + n * 16] = acc[m][n][j];
      }
  } else if (EPI == 1) {
    u16* Cb = (u16*)Cv + (size_t)bz * bC;
#pragma unroll
    for (int m = 0; m < 8; ++m)
#pragma unroll
      for (int j = 0; j < 4; ++j) {
        size_t roff = (size_t)(row0 + m * 16 + j) * N + col0;
#pragma unroll
        for (int n = 0; n < 4; ++n) Cb[roff + n * 16] = f2bf(acc[m][n][j]);
      }
  } else if (EPI == 2) {
    u16* Cb = (u16*)Cv + (size_t)bz * bC;
#pragma unroll
    for (int m = 0; m < 8; ++m)
#pragma unroll
      for (int j = 0; j < 4; ++j) {
        size_t roff = (size_t)(row0 + m * 16 + j) * N + col0;
#pragma unroll
        for (int n = 0; n < 4; ++n) {
          float v = acc[m][n][j];
          v = fminf(5.f, fmaxf(-5.f, v));
          Cb[roff + n * 16] = f2bf(silu_f(v));
        }
      }
  } else if (EPI == 3) {
    u16* Cb = (u16*)Cv + (size_t)bz * bC;
    const u16* Hb = H + (size_t)bz * bC;
#pragma unroll
    for (int m = 0; m < 8; ++m)
#pragma unroll
      for (int j = 0; j < 4; ++j) {
        size_t roff = (size_t)(row0 + m * 16 + j) * N + col0;
#pragma unroll
        for (int n = 0; n < 4; ++n) {
          size_t idx = roff + n * 16;
          Cb[idx] = f2bf(b2f(Hb[idx]) + 0.1f * acc[m][n][j]);
        }
      }
  } else {  // EPI == 4: C = silu(acc) * H
    u16* Cb = (u16*)Cv + (size_t)bz * bC;
    const u16* Hb = H + (size_t)bz * bC;
#pragma unroll
    for (int m = 0; m < 8; ++m)
#pragma unroll
      for (int j = 0; j < 4; ++j) {
        size_t roff = (size_t)(row0 + m * 16 + j) * N + col0;
#pragma unroll
        for (int n = 0; n < 4; ++n) {
          size_t idx = roff + n * 16;
          Cb[idx] = f2bf(silu_f(acc[m][n][j]) * b2f(Hb[idx]));
        }
      }
  }
}

extern "C" void kernel_launch(void* const* d_in, const int* in_sizes, int n_in,
                              void* d_out, int out_size, void* d_ws, size_t ws_size,
                              hipStream_t stream) {
  const float* x      = (const float*)d_in[0];
  const float* W_up   = (const float*)d_in[1];
  const float* W_gate = (const float*)d_in[2];
  const float* W_down = (const float*)d_in[3];
  const float* W_pre  = (const float*)d_in[4];
  const float* W_post = (const float*)d_in[5];
  const float* W_proj = (const float*)d_in[6];
  const float* ln_g   = (const float*)d_in[7];
  const float* ln_b   = (const float*)d_in[8];
  (void)in_sizes; (void)n_in; (void)out_size; (void)ws_size;

  const int D = 2048, Hh = 4096, A_ = 256, Bn = 4, S = 2048, M = 8192;

  char* p = (char*)d_ws;
  u16* xb      = (u16*)p; p += (size_t)M * D * 2;
  u16* Wup_b   = (u16*)p; p += (size_t)Hh * D * 2;
  u16* Wgate_b = (u16*)p; p += (size_t)Hh * D * 2;
  u16* Wdown_b = (u16*)p; p += (size_t)D * Hh * 2;
  u16* Wpre_b  = (u16*)p; p += (size_t)A_ * D * 2;
  u16* Wpost_b = (u16*)p; p += (size_t)A_ * Hh * 2;
  u16* Wproj_b = (u16*)p; p += (size_t)Hh * A_ * 2;
  u16* hidden  = (u16*)p; p += (size_t)M * Hh * 2;
  u16* scratch = (u16*)p; p += (size_t)M * Hh * 2;
  char* q = (char*)scratch;
  u16*   aw        = (u16*)q; q += (size_t)Bn * S * S * 2;
  u16*   adapt_in  = (u16*)q; q += (size_t)M * A_ * 2;
  u16*   adapt_inT = (u16*)q; q += (size_t)M * A_ * 2;
  u16*   adapt_out = (u16*)q; q += (size_t)M * A_ * 2;
  u16*   adaptb    = (u16*)q; q += (size_t)M * A_ * 2;
  float* pre       = (float*)q; q += (size_t)M * A_ * 4;

  auto cvt = [&](const float* src, u16* dst, size_t n) {
    int n4 = (int)(n / 4);
    cvt_k<<<dim3((n4 + 255) / 256), dim3(256), 0, stream>>>((const float4*)src, (ushort4*)dst, n4);
  };
  cvt(x,      xb,      (size_t)M * D);
  cvt(W_up,   Wup_b,   (size_t)Hh * D);
  cvt(W_gate, Wgate_b, (size_t)Hh * D);
  cvt(W_down, Wdown_b, (size_t)D * Hh);
  cvt(W_pre,  Wpre_b,  (size_t)A_ * D);
  cvt(W_post, Wpost_b, (size_t)A_ * Hh);
  cvt(W_proj, Wproj_b, (size_t)Hh * A_);

  // up = x @ W_up^T  [M,Hh] bf16
  gemm256<1><<<dim3(Hh / 256, M / 256, 1), 512, 0, stream>>>(xb, Wup_b, hidden, nullptr,
                                                             M, Hh, D, 0, 0, 0);
  // hidden = silu(x @ W_gate^T) * up   (fused epilogue, in-place on 'hidden')
  gemm256<4><<<dim3(Hh / 256, M / 256, 1), 512, 0, stream>>>(xb, Wgate_b, hidden, hidden,
                                                             M, Hh, D, 0, 0, 0);

  // adapt_in = LN(x @ W_pre^T)
  gemm_bt<0><<<dim3(A_ / 128, M / 128, 1), 256, 0, stream>>>(xb, Wpre_b, pre, M, A_, D, 0, 0, 0);
  ln_k<<<dim3(M), 256, 0, stream>>>(pre, ln_g, ln_b, adapt_in, adapt_inT);

  // adapt_out = LN(hidden @ W_post^T)
  gemm_bt<0><<<dim3(A_ / 128, M / 128, 1), 256, 0, stream>>>(hidden, Wpost_b, pre, M, A_, Hh, 0, 0, 0);
  ln_k<<<dim3(M), 256, 0, stream>>>(pre, ln_g, ln_b, adapt_out, nullptr);

  // aw[b] = silu(clip(adapt_in[b] @ adapt_out[b]^T, -5, 5))
  gemm256<2><<<dim3(S / 256, S / 256, Bn), 512, 0, stream>>>(adapt_in, adapt_out, aw, nullptr,
                                                             S, S, A_,
                                                             (long)S * A_, (long)S * A_, (long)S * S);

  // adapt[b] = aw[b] @ adapt_in[b]  (adapt_inT is [A_,S])
  gemm_bt<1><<<dim3(A_ / 128, S / 128, Bn), 256, 0, stream>>>(aw, adapt_inT, adaptb,
                                                              S, A_, S,
                                                              (long)S * S, (long)A_ * S, (long)S * A_);

  // hidden += 0.1 * adapt @ W_proj^T
  gemm256<3><<<dim3(Hh / 256, M / 256, 1), 512, 0, stream>>>(adaptb, Wproj_b, hidden, hidden,
                                                             M, Hh, A_, 0, 0, 0);

  // out = hidden @ W_down^T  [M,D] f32
  gemm256<0><<<dim3(D / 256, M / 256, 1), 512, 0, stream>>>(hidden, Wdown_b, d_out, nullptr,
                                                            M, D, Hh, 0, 0, 0);
}

// Round 4
// 622.613 us; speedup vs baseline: 1.2001x; 1.2001x over previous
//
#include <hip/hip_runtime.h>
#include <cstdint>
#include <cstddef>

typedef unsigned short u16;
typedef short short8 __attribute__((ext_vector_type(8)));
typedef float f32x4 __attribute__((ext_vector_type(4)));

__device__ __forceinline__ u16 f2bf(float f) {
  union { float f; unsigned u; } x; x.f = f;
  unsigned r = x.u + 0x7FFFu + ((x.u >> 16) & 1u);   // RNE
  return (u16)(r >> 16);
}
__device__ __forceinline__ float b2f(u16 h) {
  union { unsigned u; float f; } x; x.u = ((unsigned)h) << 16;
  return x.f;
}
__device__ __forceinline__ float silu_f(float v) {
  return v / (1.f + __expf(-v));
}
__device__ __forceinline__ void gll(const u16* g, u16* l) {
  __builtin_amdgcn_global_load_lds((const __attribute__((address_space(1))) unsigned*)g,
                                   (__attribute__((address_space(3))) unsigned*)l, 16, 0, 0);
}

// ---------------- f32 -> bf16 conversion (vectorized) ----------------
__global__ __launch_bounds__(256) void cvt_k(const float4* __restrict__ in,
                                             ushort4* __restrict__ out, int n4) {
  int i = blockIdx.x * 256 + threadIdx.x;
  if (i >= n4) return;
  float4 v = in[i];
  ushort4 o;
  o.x = f2bf(v.x); o.y = f2bf(v.y); o.z = f2bf(v.z); o.w = f2bf(v.w);
  out[i] = o;
}

// ---------------- reduce 4 split-K partials + LayerNorm over 256 cols ----------------
// part: [4][Mtot][256] f32.  out: [Mtot,256] bf16.  outT (optional): [4][256][2048].
__global__ __launch_bounds__(256) void red_ln_k(const float* __restrict__ part,
                                                const float* __restrict__ g,
                                                const float* __restrict__ b,
                                                u16* __restrict__ out,
                                                u16* __restrict__ outT, int Mtot) {
  const int row = blockIdx.x;
  const int a = threadIdx.x;
  const size_t stride = (size_t)Mtot * 256;
  const size_t base = (size_t)row * 256 + a;
  float v = part[base] + part[base + stride] + part[base + 2 * stride] + part[base + 3 * stride];
  float s = v, s2 = v * v;
#pragma unroll
  for (int o = 32; o; o >>= 1) { s += __shfl_down(s, o, 64); s2 += __shfl_down(s2, o, 64); }
  __shared__ float red[8];
  int l = a & 63, w = a >> 6;
  if (l == 0) { red[w] = s; red[4 + w] = s2; }
  __syncthreads();
  s  = red[0] + red[1] + red[2] + red[3];
  s2 = red[4] + red[5] + red[6] + red[7];
  float mu  = s * 0.00390625f;
  float var = s2 * 0.00390625f - mu * mu;
  float rs  = rsqrtf(var + 1e-5f);
  float o   = (v - mu) * rs * g[a] + b[a];
  u16 ob = f2bf(o);
  out[base] = ob;
  if (outT) {
    int bi = row >> 11, t = row & 2047;
    outT[((size_t)bi * 256 + a) * 2048 + t] = ob;
  }
}

// ---------------- reduce 4 split-K partials -> bf16 ----------------
__global__ __launch_bounds__(256) void red_k(const float* __restrict__ part,
                                             u16* __restrict__ out, int Mtot) {
  const int row = blockIdx.x;
  const int a = threadIdx.x;
  const size_t stride = (size_t)Mtot * 256;
  const size_t base = (size_t)row * 256 + a;
  float v = part[base] + part[base + stride] + part[base + 2 * stride] + part[base + 3 * stride];
  out[base] = f2bf(v);
}

// ================= 128x128 2-phase GEMM ============
// EPI: 1 = bf16 store, 2 = silu(clip(v,-5,5)) bf16 store
template <int EPI>
__global__ __launch_bounds__(256) void gemm_bt(const u16* __restrict__ A,
                                               const u16* __restrict__ B,
                                               void* __restrict__ Cv,
                                               int M, int N, int K,
                                               long bA, long bB, long bC) {
  __shared__ u16 Al[128 * 64];
  __shared__ u16 Bl[128 * 64];
  const int tid  = threadIdx.x;
  const int bz   = blockIdx.z;
  const int brow = blockIdx.y * 128;
  const int bcol = blockIdx.x * 128;
  A += (size_t)bz * bA;
  B += (size_t)bz * bB;
  const int lane = tid & 63;
  const int w = tid >> 6, wr = w >> 1, wc = w & 1;
  const int srow = tid >> 3;
  const int scol = (tid & 7) * 8;

  f32x4 acc[4][4] = {};

  for (int kt = 0; kt < K; kt += 64) {
#pragma unroll
    for (int i = 0; i < 4; ++i)
      gll(A + (size_t)(brow + i * 32 + srow) * K + kt + scol, &Al[(i * 256 + tid) * 8]);
#pragma unroll
    for (int i = 0; i < 4; ++i)
      gll(B + (size_t)(bcol + i * 32 + srow) * K + kt + scol, &Bl[(i * 256 + tid) * 8]);
    __syncthreads();
#pragma unroll
    for (int kk = 0; kk < 2; ++kk) {
      short8 af[4], bfr[4];
      const int ko = kk * 32 + (lane >> 4) * 8;
#pragma unroll
      for (int m = 0; m < 4; ++m)
        af[m] = *(const short8*)&Al[(wr * 64 + m * 16 + (lane & 15)) * 64 + ko];
#pragma unroll
      for (int n = 0; n < 4; ++n)
        bfr[n] = *(const short8*)&Bl[(wc * 64 + n * 16 + (lane & 15)) * 64 + ko];
#pragma unroll
      for (int m = 0; m < 4; ++m)
#pragma unroll
        for (int n = 0; n < 4; ++n)
          acc[m][n] = __builtin_amdgcn_mfma_f32_16x16x32_bf16(af[m], bfr[n], acc[m][n], 0, 0, 0);
    }
    __syncthreads();
  }

  const int col0 = bcol + wc * 64 + (lane & 15);
  const int row0 = brow + wr * 64 + ((lane >> 4) << 2);
  u16* Cb = (u16*)Cv + (size_t)bz * bC;
#pragma unroll
  for (int m = 0; m < 4; ++m)
#pragma unroll
    for (int j = 0; j < 4; ++j) {
      size_t roff = (size_t)(row0 + m * 16 + j) * N + col0;
#pragma unroll
      for (int n = 0; n < 4; ++n) {
        float v = acc[m][n][j];
        if (EPI == 2) {
          v = fminf(5.f, fmaxf(-5.f, v));
          v = silu_f(v);
        }
        Cb[roff + n * 16] = f2bf(v);
      }
    }
}

// ================= 128x128 split-K (SK=4) partial GEMM: f32 partials =================
// blockIdx.z = b*4 + sk.  A row stride = Kfull; computes K range [sk*Kc, (sk+1)*Kc).
// part[((sk*Mtot) + b*M + row)*256... general N] layout: [sk][Mtot rows][N] f32.
__global__ __launch_bounds__(256) void gemm_sk(const u16* __restrict__ A,
                                               const u16* __restrict__ B,
                                               float* __restrict__ part,
                                               int M, int N, int Kfull, int Kc,
                                               long bA, long bB, int Mtot) {
  const int z  = blockIdx.z;
  const int b  = z >> 2, sk = z & 3;
  const int brow = blockIdx.y * 128;
  const int bcol = blockIdx.x * 128;
  A += (size_t)b * bA + (size_t)sk * Kc;
  B += (size_t)b * bB + (size_t)sk * Kc;

  __shared__ u16 Al[128 * 64];
  __shared__ u16 Bl[128 * 64];
  const int tid  = threadIdx.x;
  const int lane = tid & 63;
  const int w = tid >> 6, wr = w >> 1, wc = w & 1;
  const int srow = tid >> 3;
  const int scol = (tid & 7) * 8;

  f32x4 acc[4][4] = {};

  for (int kt = 0; kt < Kc; kt += 64) {
#pragma unroll
    for (int i = 0; i < 4; ++i)
      gll(A + (size_t)(brow + i * 32 + srow) * Kfull + kt + scol, &Al[(i * 256 + tid) * 8]);
#pragma unroll
    for (int i = 0; i < 4; ++i)
      gll(B + (size_t)(bcol + i * 32 + srow) * Kfull + kt + scol, &Bl[(i * 256 + tid) * 8]);
    __syncthreads();
#pragma unroll
    for (int kk = 0; kk < 2; ++kk) {
      short8 af[4], bfr[4];
      const int ko = kk * 32 + (lane >> 4) * 8;
#pragma unroll
      for (int m = 0; m < 4; ++m)
        af[m] = *(const short8*)&Al[(wr * 64 + m * 16 + (lane & 15)) * 64 + ko];
#pragma unroll
      for (int n = 0; n < 4; ++n)
        bfr[n] = *(const short8*)&Bl[(wc * 64 + n * 16 + (lane & 15)) * 64 + ko];
#pragma unroll
      for (int m = 0; m < 4; ++m)
#pragma unroll
        for (int n = 0; n < 4; ++n)
          acc[m][n] = __builtin_amdgcn_mfma_f32_16x16x32_bf16(af[m], bfr[n], acc[m][n], 0, 0, 0);
    }
    __syncthreads();
  }

  const int col0 = bcol + wc * 64 + (lane & 15);
  const int row0 = brow + wr * 64 + ((lane >> 4) << 2);
  float* P = part + ((size_t)sk * Mtot + (size_t)b * M) * N;
#pragma unroll
  for (int m = 0; m < 4; ++m)
#pragma unroll
    for (int j = 0; j < 4; ++j) {
      size_t roff = (size_t)(row0 + m * 16 + j) * N + col0;
#pragma unroll
      for (int n = 0; n < 4; ++n) P[roff + n * 16] = acc[m][n][j];
    }
}

// ================= 256x256 8-wave pipelined GEMM (round-2 schedule, verified 155us) =========
// EPI: 0=f32, 1=bf16, 2=silu(clip(v,-5,5)) bf16, 3=bf16(H+0.1*v), 4=bf16(silu(v)*H)
template <int EPI>
__global__ __launch_bounds__(512, 2) void gemm256(const u16* __restrict__ A,
                                                  const u16* __restrict__ B,
                                                  void* __restrict__ Cv,
                                                  const u16* __restrict__ H,
                                                  int M, int N, int K,
                                                  long bA, long bB, long bC) {
  __shared__ __align__(16) u16 As[32768];  // [2 buf][2 half][128][64]
  __shared__ __align__(16) u16 Bs[32768];

  const int tid = threadIdx.x;
  const int bz  = blockIdx.z;
  A += (size_t)bz * bA;
  B += (size_t)bz * bB;

  // T1: bijective XCD swizzle (m204)
  const int gx = gridDim.x;
  const int nwg = gx * gridDim.y;
  int orig = blockIdx.y * gx + blockIdx.x;
  {
    int q = nwg >> 3, r = nwg & 7;
    int xcd = orig & 7, idx = orig >> 3;
    orig = (xcd < r) ? xcd * (q + 1) + idx : r * (q + 1) + (xcd - r) * q + idx;
  }
  const int brow = (orig / gx) * 256;
  const int bcol = (orig % gx) * 256;

  const int lane = tid & 63;
  const int wid  = tid >> 6;
  const int wm = wid >> 2, wn = wid & 3;   // 2 x 4 waves

  const int srow = tid >> 3;
  const int scol = ((((tid & 7) << 4) ^ ((srow & 7) << 4)) >> 1);  // u16 units, T2 swizzle
  const u16* Abase = A + (size_t)(brow + srow) * K + scol;
  const u16* Bbase = B + (size_t)(bcol + srow) * K + scol;

  const int fr  = lane & 15;
  const int cs0 = ((((lane >> 4) << 4) ^ ((lane & 7) << 4)) >> 1);
  const int cs1 = cs0 ^ 32;
  const int bro = (wn & 1) * 64;

  const int NT = K >> 6;

  f32x4 acc[8][4] = {};

  // ---- prologue: stage tile 0 into buf 0 ----
  {
#pragma unroll
    for (int h = 0; h < 2; ++h) {
      const u16* s = Abase + (size_t)(h * 128) * K;
      u16* d = &As[h * 8192 + tid * 8];
      gll(s, d); gll(s + (size_t)64 * K, d + 4096);
    }
#pragma unroll
    for (int h = 0; h < 2; ++h) {
      const u16* s = Bbase + (size_t)(h * 128) * K;
      u16* d = &Bs[h * 8192 + tid * 8];
      gll(s, d); gll(s + (size_t)64 * K, d + 4096);
    }
  }
  asm volatile("s_waitcnt vmcnt(0)" ::: "memory");
  __builtin_amdgcn_s_barrier();

  for (int t = 0; t < NT; ++t) {
    const int cur = t & 1, nxt = cur ^ 1;
    const bool pf = (t + 1 < NT);
    const int ktn = (t + 1) << 6;
    const u16* aH = &As[(cur * 2 + wm) * 8192];
    const u16* bH = &Bs[(cur * 2 + (wn >> 1)) * 8192];
    short8 af[4], bf[4];

    // ---------- phase 0: mq=0, kq=0; prefetch A halves of t+1 ----------
#pragma unroll
    for (int m = 0; m < 4; ++m) af[m] = *(const short8*)(aH + (m * 16 + fr) * 64 + cs0);
#pragma unroll
    for (int n = 0; n < 4; ++n) bf[n] = *(const short8*)(bH + (bro + n * 16 + fr) * 64 + cs0);
    if (pf) {
#pragma unroll
      for (int h = 0; h < 2; ++h) {
        const u16* s = Abase + (size_t)(h * 128) * K + ktn;
        u16* d = &As[(nxt * 2 + h) * 8192 + tid * 8];
        gll(s, d); gll(s + (size_t)64 * K, d + 4096);
      }
    }
    __builtin_amdgcn_s_barrier();
    asm volatile("s_waitcnt lgkmcnt(0)" ::: "memory");
    __builtin_amdgcn_s_setprio(1);
#pragma unroll
    for (int m = 0; m < 4; ++m)
#pragma unroll
      for (int n = 0; n < 4; ++n)
        acc[m][n] = __builtin_amdgcn_mfma_f32_16x16x32_bf16(af[m], bf[n], acc[m][n], 0, 0, 0);
    __builtin_amdgcn_s_setprio(0);
    __builtin_amdgcn_s_barrier();

    // ---------- phase 1: mq=1, kq=0; prefetch B halves of t+1 ----------
#pragma unroll
    for (int m = 0; m < 4; ++m) af[m] = *(const short8*)(aH + (64 + m * 16 + fr) * 64 + cs0);
    if (pf) {
#pragma unroll
      for (int h = 0; h < 2; ++h) {
        const u16* s = Bbase + (size_t)(h * 128) * K + ktn;
        u16* d = &Bs[(nxt * 2 + h) * 8192 + tid * 8];
        gll(s, d); gll(s + (size_t)64 * K, d + 4096);
      }
    }
    __builtin_amdgcn_s_barrier();
    asm volatile("s_waitcnt lgkmcnt(0)" ::: "memory");
    __builtin_amdgcn_s_setprio(1);
#pragma unroll
    for (int m = 0; m < 4; ++m)
#pragma unroll
      for (int n = 0; n < 4; ++n)
        acc[4 + m][n] = __builtin_amdgcn_mfma_f32_16x16x32_bf16(af[m], bf[n], acc[4 + m][n], 0, 0, 0);
    __builtin_amdgcn_s_setprio(0);
    __builtin_amdgcn_s_barrier();

    // ---------- phase 2: mq=0, kq=1 ----------
#pragma unroll
    for (int m = 0; m < 4; ++m) af[m] = *(const short8*)(aH + (m * 16 + fr) * 64 + cs1);
#pragma unroll
    for (int n = 0; n < 4; ++n) bf[n] = *(const short8*)(bH + (bro + n * 16 + fr) * 64 + cs1);
    __builtin_amdgcn_s_barrier();
    asm volatile("s_waitcnt lgkmcnt(0)" ::: "memory");
    __builtin_amdgcn_s_setprio(1);
#pragma unroll
    for (int m = 0; m < 4; ++m)
#pragma unroll
      for (int n = 0; n < 4; ++n)
        acc[m][n] = __builtin_amdgcn_mfma_f32_16x16x32_bf16(af[m], bf[n], acc[m][n], 0, 0, 0);
    __builtin_amdgcn_s_setprio(0);
    __builtin_amdgcn_s_barrier();

    // ---------- phase 3: mq=1, kq=1; tile-boundary fence ----------
#pragma unroll
    for (int m = 0; m < 4; ++m) af[m] = *(const short8*)(aH + (64 + m * 16 + fr) * 64 + cs1);
    __builtin_amdgcn_s_barrier();
    asm volatile("s_waitcnt lgkmcnt(0)" ::: "memory");
    __builtin_amdgcn_s_setprio(1);
#pragma unroll
    for (int m = 0; m < 4; ++m)
#pragma unroll
      for (int n = 0; n < 4; ++n)
        acc[4 + m][n] = __builtin_amdgcn_mfma_f32_16x16x32_bf16(af[m], bf[n], acc[4 + m][n], 0, 0, 0);
    __builtin_amdgcn_s_setprio(0);
    asm volatile("s_waitcnt vmcnt(0)" ::: "memory");   // tile t+1 loads (issued phases 0-1) complete
    __builtin_amdgcn_s_barrier();
  }

  // ---- epilogue.  C/D layout: col = lane&15, row = (lane>>4)*4 + reg ----
  const int col0 = bcol + wn * 64 + fr;
  const int row0 = brow + wm * 128 + ((lane >> 4) << 2);

  if (EPI == 0) {
    float* Cf = (float*)Cv + (size_t)bz * bC;
#pragma unroll
    for (int m = 0; m < 8; ++m)
#pragma unroll
      for (int j = 0; j < 4; ++j) {
        size_t roff = (size_t)(row0 + m * 16 + j) * N + col0;
#pragma unroll
        for (int n = 0; n < 4; ++n) Cf[roff + n * 16] = acc[m][n][j];
      }
  } else if (EPI == 1) {
    u16* Cb = (u16*)Cv + (size_t)bz * bC;
#pragma unroll
    for (int m = 0; m < 8; ++m)
#pragma unroll
      for (int j = 0; j < 4; ++j) {
        size_t roff = (size_t)(row0 + m * 16 + j) * N + col0;
#pragma unroll
        for (int n = 0; n < 4; ++n) Cb[roff + n * 16] = f2bf(acc[m][n][j]);
      }
  } else if (EPI == 2) {
    u16* Cb = (u16*)Cv + (size_t)bz * bC;
#pragma unroll
    for (int m = 0; m < 8; ++m)
#pragma unroll
      for (int j = 0; j < 4; ++j) {
        size_t roff = (size_t)(row0 + m * 16 + j) * N + col0;
#pragma unroll
        for (int n = 0; n < 4; ++n) {
          float v = acc[m][n][j];
          v = fminf(5.f, fmaxf(-5.f, v));
          Cb[roff + n * 16] = f2bf(silu_f(v));
        }
      }
  } else if (EPI == 3) {
    u16* Cb = (u16*)Cv + (size_t)bz * bC;
    const u16* Hb = H + (size_t)bz * bC;
#pragma unroll
    for (int m = 0; m < 8; ++m)
#pragma unroll
      for (int j = 0; j < 4; ++j) {
        size_t roff = (size_t)(row0 + m * 16 + j) * N + col0;
#pragma unroll
        for (int n = 0; n < 4; ++n) {
          size_t idx = roff + n * 16;
          Cb[idx] = f2bf(b2f(Hb[idx]) + 0.1f * acc[m][n][j]);
        }
      }
  } else {  // EPI == 4: C = silu(acc) * H
    u16* Cb = (u16*)Cv + (size_t)bz * bC;
    const u16* Hb = H + (size_t)bz * bC;
#pragma unroll
    for (int m = 0; m < 8; ++m)
#pragma unroll
      for (int j = 0; j < 4; ++j) {
        size_t roff = (size_t)(row0 + m * 16 + j) * N + col0;
#pragma unroll
        for (int n = 0; n < 4; ++n) {
          size_t idx = roff + n * 16;
          Cb[idx] = f2bf(silu_f(acc[m][n][j]) * b2f(Hb[idx]));
        }
      }
  }
}

extern "C" void kernel_launch(void* const* d_in, const int* in_sizes, int n_in,
                              void* d_out, int out_size, void* d_ws, size_t ws_size,
                              hipStream_t stream) {
  const float* x      = (const float*)d_in[0];
  const float* W_up   = (const float*)d_in[1];
  const float* W_gate = (const float*)d_in[2];
  const float* W_down = (const float*)d_in[3];
  const float* W_pre  = (const float*)d_in[4];
  const float* W_post = (const float*)d_in[5];
  const float* W_proj = (const float*)d_in[6];
  const float* ln_g   = (const float*)d_in[7];
  const float* ln_b   = (const float*)d_in[8];
  (void)in_sizes; (void)n_in; (void)out_size; (void)ws_size;

  const int D = 2048, Hh = 4096, A_ = 256, Bn = 4, S = 2048, M = 8192;

  char* p = (char*)d_ws;
  u16* xb      = (u16*)p; p += (size_t)M * D * 2;
  u16* Wup_b   = (u16*)p; p += (size_t)Hh * D * 2;    // becomes split-K partials after gate GEMM
  u16* Wgate_b = (u16*)p; p += (size_t)Hh * D * 2;
  u16* Wdown_b = (u16*)p; p += (size_t)D * Hh * 2;
  u16* Wpre_b  = (u16*)p; p += (size_t)A_ * D * 2;
  u16* Wpost_b = (u16*)p; p += (size_t)A_ * Hh * 2;
  u16* Wproj_b = (u16*)p; p += (size_t)Hh * A_ * 2;
  u16* hidden  = (u16*)p; p += (size_t)M * Hh * 2;
  u16* scratch = (u16*)p; p += (size_t)M * Hh * 2;
  char* q = (char*)scratch;
  u16*   aw        = (u16*)q; q += (size_t)Bn * S * S * 2;
  u16*   adapt_in  = (u16*)q; q += (size_t)M * A_ * 2;
  u16*   adapt_inT = (u16*)q; q += (size_t)M * A_ * 2;
  u16*   adapt_out = (u16*)q; q += (size_t)M * A_ * 2;
  u16*   adaptb    = (u16*)q; q += (size_t)M * A_ * 2;
  // split-K partials: [4][8192][256] f32 = 33.5 MB, exactly the (dead-after-gate) Wup+Wgate region
  float* part = (float*)Wup_b;

  auto cvt = [&](const float* src, u16* dst, size_t n) {
    int n4 = (int)(n / 4);
    cvt_k<<<dim3((n4 + 255) / 256), dim3(256), 0, stream>>>((const float4*)src, (ushort4*)dst, n4);
  };
  cvt(x,      xb,      (size_t)M * D);
  cvt(W_up,   Wup_b,   (size_t)Hh * D);
  cvt(W_gate, Wgate_b, (size_t)Hh * D);
  cvt(W_down, Wdown_b, (size_t)D * Hh);
  cvt(W_pre,  Wpre_b,  (size_t)A_ * D);
  cvt(W_post, Wpost_b, (size_t)A_ * Hh);
  cvt(W_proj, Wproj_b, (size_t)Hh * A_);

  // up = x @ W_up^T  [M,Hh] bf16
  gemm256<1><<<dim3(Hh / 256, M / 256, 1), 512, 0, stream>>>(xb, Wup_b, hidden, nullptr,
                                                             M, Hh, D, 0, 0, 0);
  // hidden = silu(x @ W_gate^T) * up   (fused epilogue, in-place)
  gemm256<4><<<dim3(Hh / 256, M / 256, 1), 512, 0, stream>>>(xb, Wgate_b, hidden, hidden,
                                                             M, Hh, D, 0, 0, 0);
  // (Wup_b/Wgate_b now dead -> 'part' region live)

  // adapt_in = LN(x @ W_pre^T)  — split-K(4) + fused reduce/LN
  gemm_sk<<<dim3(A_ / 128, M / 128, 4), 256, 0, stream>>>(xb, Wpre_b, part,
                                                          M, A_, D, D / 4, 0, 0, M);
  red_ln_k<<<dim3(M), 256, 0, stream>>>(part, ln_g, ln_b, adapt_in, adapt_inT, M);

  // adapt_out = LN(hidden @ W_post^T)  — split-K(4)
  gemm_sk<<<dim3(A_ / 128, M / 128, 4), 256, 0, stream>>>(hidden, Wpost_b, part,
                                                          M, A_, Hh, Hh / 4, 0, 0, M);
  red_ln_k<<<dim3(M), 256, 0, stream>>>(part, ln_g, ln_b, adapt_out, nullptr, M);

  // aw[b] = silu(clip(adapt_in[b] @ adapt_out[b]^T, -5, 5))  — 128^2, 1024 blocks
  gemm_bt<2><<<dim3(S / 128, S / 128, Bn), 256, 0, stream>>>(adapt_in, adapt_out, aw,
                                                             S, S, A_,
                                                             (long)S * A_, (long)S * A_, (long)S * S);

  // adapt[b] = aw[b] @ adapt_in[b]  — split-K(4) over K=S, batched (z = b*4+sk)
  gemm_sk<<<dim3(A_ / 128, S / 128, Bn * 4), 256, 0, stream>>>(aw, adapt_inT, part,
                                                               S, A_, S, S / 4,
                                                               (long)S * S, (long)A_ * S, M);
  red_k<<<dim3(M), 256, 0, stream>>>(part, adaptb, M);

  // hidden += 0.1 * adapt @ W_proj^T
  gemm256<3><<<dim3(Hh / 256, M / 256, 1), 512, 0, stream>>>(adaptb, Wproj_b, hidden, hidden,
                                                             M, Hh, A_, 0, 0, 0);

  // out = hidden @ W_down^T  [M,D] f32
  gemm256<0><<<dim3(D / 256, M / 256, 1), 512, 0, stream>>>(hidden, Wdown_b, d_out, nullptr,
                                                            M, D, Hh, 0, 0, 0);
}